// Round 1
// baseline (29227.856 us; speedup 1.0000x reference)
//
#include <hip/hip_runtime.h>
#include <hip/hip_bf16.h>
#include <cstdint>
#include <cstddef>

#define T_DIM 512
#define B_DIM 256
#define D_DIM 256
#define H_DIM 512
#define O_DIM 256
#define NSTEP 10

__device__ __forceinline__ unsigned short f2bf(float f) {
    __hip_bfloat16 b = __float2bfloat16(f);   // RNE
    return *reinterpret_cast<unsigned short*>(&b);
}

// ---------------- transposes (tiny) ----------------
__global__ void k_transpose(const float* __restrict__ W_hh,
                            const float* __restrict__ W_ih,
                            const float* __restrict__ W_out,
                            float* __restrict__ whhT,   // [512][512] k-major
                            float* __restrict__ wihT,   // [256][512] d-major
                            float* __restrict__ woutT)  // [512][256] h-major
{
    int idx = blockIdx.x * blockDim.x + threadIdx.x;
    if (idx < 512 * 512) {
        int k = idx >> 9, h = idx & 511;
        whhT[k * 512 + h] = W_hh[h * 512 + k];
    } else if (idx < 512 * 512 + 256 * 512) {
        int j = idx - 512 * 512;
        int d = j >> 9, h = j & 511;
        wihT[d * 512 + h] = W_ih[h * 257 + d];   // note: W_ih row length = 257
    } else if (idx < 512 * 512 + 256 * 512 + 512 * 256) {
        int j = idx - (512 * 512 + 256 * 512);
        int h = j >> 8, o = j & 255;
        woutT[h * 256 + o] = W_out[o * 512 + h];
    }
}

// ---------------- xc = x @ W_ih[:, :D].T + (b_ih + b_hh) ----------------
__global__ __launch_bounds__(512) void k_xc(
    const float* __restrict__ x,     // [T*B, 256]
    const float* __restrict__ wihT,  // [256][512]
    const float* __restrict__ b_ih,
    const float* __restrict__ b_hh,
    float* __restrict__ xc)          // [T*B, 512]
{
    __shared__ float xl[16][256];
    const int tid = threadIdx.x;
    const int tb0 = blockIdx.x * 16;
    for (int i = tid; i < 16 * 256; i += 512)
        xl[i >> 8][i & 255] = x[(size_t)tb0 * 256 + i];
    __syncthreads();
    const int h = tid;
    float acc[16];
#pragma unroll
    for (int r = 0; r < 16; ++r) acc[r] = 0.f;
    for (int d = 0; d < 256; d += 4) {
        const float wv0 = wihT[(d + 0) * 512 + h];
        const float wv1 = wihT[(d + 1) * 512 + h];
        const float wv2 = wihT[(d + 2) * 512 + h];
        const float wv3 = wihT[(d + 3) * 512 + h];
#pragma unroll
        for (int r = 0; r < 16; ++r) {
            const float4 xv = *(const float4*)&xl[r][d];
            acc[r] += xv.x * wv0;
            acc[r] += xv.y * wv1;
            acc[r] += xv.z * wv2;
            acc[r] += xv.w * wv3;
        }
    }
    const float bias = b_ih[h] + b_hh[h];
    for (int r = 0; r < 16; ++r)
        xc[(size_t)(tb0 + r) * 512 + h] = acc[r] + bias;
}

// ---------------- sequential ACT recurrence ----------------
// 64 blocks x 256 threads; block owns 4 batch rows; thread owns h0=2*tid, h0+1.
__global__ __launch_bounds__(256) void k_recur(
    const float* __restrict__ xc,    // [T*B,512] (may be null -> compute in-loop)
    const float* __restrict__ x,     // [T,B,256]
    const float* __restrict__ wihT,  // [256][512]
    const float* __restrict__ b_ih,
    const float* __restrict__ b_hh,
    const float* __restrict__ whhT,  // [512][512] k-major
    const float* __restrict__ W_ih,  // flag col at [h*257+256]
    const float* __restrict__ w_halt,
    const float* __restrict__ b_halt,
    float* out,                      // d_out (y region reused as bf16 s_acc)
    float* __restrict__ psum_g)      // [T*B]
{
    __shared__ __align__(16) float sb[2][4][512];  // s ping-pong
    __shared__ float xl[4][256];
    __shared__ float whalt_l[512];
    __shared__ float flag_l[512];
    __shared__ float bias_l[512];
    __shared__ float red[4][4];  // [wave][row]

    const int tid = threadIdx.x;
    const int b0 = blockIdx.x * 4;
    const int h0 = tid * 2;
    const int wave = tid >> 6;
    const int lane = tid & 63;

    for (int i = tid; i < 512; i += 256) {
        whalt_l[i] = w_halt[i];
        flag_l[i] = W_ih[i * 257 + 256];
        bias_l[i] = b_ih[i] + b_hh[i];
    }
    for (int i = tid; i < 4 * 512; i += 256) sb[0][i >> 9][i & 511] = 0.f;
    __syncthreads();

    const float bh = b_halt[0];
    const float THR = 1.0f - 0.01f;
    unsigned short* sacc_out = (unsigned short*)out;  // bf16 staging in y region
    float* rho_out = out + (size_t)T_DIM * B_DIM * O_DIM;
    float* n_out = rho_out + (size_t)T_DIM * B_DIM;

    int cur = 0;
    for (int t = 0; t < T_DIM; ++t) {
        float xcv[4][2];
        if (xc) {
#pragma unroll
            for (int r = 0; r < 4; ++r) {
                const float2 v =
                    *(const float2*)&xc[(size_t)(t * B_DIM + b0 + r) * 512 + h0];
                xcv[r][0] = v.x;
                xcv[r][1] = v.y;
            }
        } else {
            for (int i = tid; i < 4 * 256; i += 256)
                xl[i >> 8][i & 255] =
                    x[(size_t)t * B_DIM * D_DIM + (size_t)(b0 + (i >> 8)) * D_DIM + (i & 255)];
            __syncthreads();
#pragma unroll
            for (int r = 0; r < 4; ++r) { xcv[r][0] = 0.f; xcv[r][1] = 0.f; }
            for (int d = 0; d < 256; ++d) {
                const float2 wv = *(const float2*)&wihT[d * 512 + h0];
#pragma unroll
                for (int r = 0; r < 4; ++r) {
                    xcv[r][0] += xl[r][d] * wv.x;
                    xcv[r][1] += xl[r][d] * wv.y;
                }
            }
#pragma unroll
            for (int r = 0; r < 4; ++r) {
                xcv[r][0] += bias_l[h0];
                xcv[r][1] += bias_l[h0 + 1];
            }
        }

        float sacc[4][2] = {};
        float hsum[4] = {}, runf[4] = {1.f, 1.f, 1.f, 1.f};
        float stepsf[4] = {}, remf[4] = {}, psum[4] = {};

        for (int nstep = 0; nstep < NSTEP; ++nstep) {
            float pre[4][2];
#pragma unroll
            for (int r = 0; r < 4; ++r) {
                pre[r][0] = xcv[r][0];
                pre[r][1] = xcv[r][1];
            }
            if (nstep == 0) {
#pragma unroll
                for (int r = 0; r < 4; ++r) {
                    pre[r][0] += flag_l[h0];
                    pre[r][1] += flag_l[h0 + 1];
                }
            }
            // pre += s @ W_hh.T   (s broadcast from LDS, W_hh^T streamed, coalesced)
            for (int k = 0; k < 512; k += 4) {
                float4 sv[4];
#pragma unroll
                for (int r = 0; r < 4; ++r) sv[r] = *(const float4*)&sb[cur][r][k];
#pragma unroll
                for (int kk = 0; kk < 4; ++kk) {
                    const float2 wv = *(const float2*)&whhT[(size_t)(k + kk) * 512 + h0];
#pragma unroll
                    for (int r = 0; r < 4; ++r) {
                        const float s = (&sv[r].x)[kk];
                        pre[r][0] += s * wv.x;
                        pre[r][1] += s * wv.y;
                    }
                }
            }
            float sn[4][2], part[4];
#pragma unroll
            for (int r = 0; r < 4; ++r) {
                sn[r][0] = tanhf(pre[r][0]);
                sn[r][1] = tanhf(pre[r][1]);
                sb[cur ^ 1][r][h0] = sn[r][0];
                sb[cur ^ 1][r][h0 + 1] = sn[r][1];
                part[r] = sn[r][0] * whalt_l[h0] + sn[r][1] * whalt_l[h0 + 1];
            }
            // butterfly wave reduce (identical association tree on every lane)
#pragma unroll
            for (int m = 1; m < 64; m <<= 1) {
#pragma unroll
                for (int r = 0; r < 4; ++r) part[r] += __shfl_xor(part[r], m, 64);
            }
            if (lane == 0) {
#pragma unroll
                for (int r = 0; r < 4; ++r) red[wave][r] = part[r];
            }
            __syncthreads();
            bool anyrun = false;
#pragma unroll
            for (int r = 0; r < 4; ++r) {
                const float dot = red[0][r] + red[1][r] + red[2][r] + red[3][r];
                const float z = dot + bh;
                const float hn = 1.f / (1.f + expf(-z));
                const float ns = hsum[r] + hn;
                const float stop = (ns >= THR) ? runf[r] : 0.f;
                const float still = runf[r] - stop;
                const float rem = (1.f - hsum[r]) * stop;
                const float p = hn * still + rem;
                sacc[r][0] += p * sn[r][0];
                sacc[r][1] += p * sn[r][1];
                psum[r] += p;
                stepsf[r] += runf[r];   // old running, matches reference order
                remf[r] += rem;
                hsum[r] = ns;
                runf[r] = still;
                anyrun = anyrun || (still != 0.f);
            }
            cur ^= 1;
            if (!anyrun) break;  // uniform: all lanes computed identical scalars
        }

        // epilogue: s(next t) = s_acc; store bf16 s_acc, psum, rho, n
#pragma unroll
        for (int r = 0; r < 4; ++r) {
            sb[cur][r][h0] = sacc[r][0];
            sb[cur][r][h0 + 1] = sacc[r][1];
            const size_t base = ((size_t)(t * B_DIM + b0 + r)) * 512 + h0;
            sacc_out[base] = f2bf(sacc[r][0]);
            sacc_out[base + 1] = f2bf(sacc[r][1]);
        }
        if (tid < 4) {
            const int r = tid;
            psum_g[t * B_DIM + b0 + r] = psum[r];
            rho_out[t * B_DIM + b0 + r] = stepsf[r] + remf[r];
            n_out[t * B_DIM + b0 + r] = stepsf[r];
        }
        __syncthreads();
    }
}

// ---------------- y = s_acc @ W_out.T + psum * b_out ----------------
// Reads bf16 s_acc from the y region of d_out, overwrites same rows with y.
__global__ __launch_bounds__(256) void k_y(
    const float* __restrict__ woutT,  // [512][256]
    const float* __restrict__ b_out,
    const float* __restrict__ psum_g,
    float* out)
{
    __shared__ float sl[16][512];
    __shared__ float pl[16];
    const int tid = threadIdx.x;
    const int tb0 = blockIdx.x * 16;
    const unsigned short* sacc = (const unsigned short*)out;
    for (int i = tid; i < 16 * 512; i += 256) {
        unsigned int u = sacc[(size_t)tb0 * 512 + i];
        u <<= 16;
        sl[i >> 9][i & 511] = __uint_as_float(u);
    }
    if (tid < 16) pl[tid] = psum_g[tb0 + tid];
    __syncthreads();
    const int o = tid;
    float acc[16];
#pragma unroll
    for (int r = 0; r < 16; ++r) acc[r] = 0.f;
    for (int h = 0; h < 512; h += 4) {
        const float wv0 = woutT[(h + 0) * 256 + o];
        const float wv1 = woutT[(h + 1) * 256 + o];
        const float wv2 = woutT[(h + 2) * 256 + o];
        const float wv3 = woutT[(h + 3) * 256 + o];
#pragma unroll
        for (int r = 0; r < 16; ++r) {
            const float4 sv = *(const float4*)&sl[r][h];
            acc[r] += sv.x * wv0;
            acc[r] += sv.y * wv1;
            acc[r] += sv.z * wv2;
            acc[r] += sv.w * wv3;
        }
    }
    const float bo = b_out[o];
    for (int r = 0; r < 16; ++r)
        out[(size_t)(tb0 + r) * 256 + o] = acc[r] + pl[r] * bo;
}

extern "C" void kernel_launch(void* const* d_in, const int* in_sizes, int n_in,
                              void* d_out, int out_size, void* d_ws, size_t ws_size,
                              hipStream_t stream) {
    const float* x = (const float*)d_in[0];
    const float* W_ih = (const float*)d_in[1];
    const float* b_ih = (const float*)d_in[2];
    const float* W_hh = (const float*)d_in[3];
    const float* b_hh = (const float*)d_in[4];
    const float* W_halt = (const float*)d_in[5];
    const float* b_halt = (const float*)d_in[6];
    const float* W_out = (const float*)d_in[7];
    const float* b_out = (const float*)d_in[8];
    float* out = (float*)d_out;

    char* ws = (char*)d_ws;
    float* whhT = (float*)ws;                                   // 1 MB
    float* wihT = (float*)(ws + (1u << 20));                    // 512 KB
    float* woutT = (float*)(ws + (1u << 20) + (512u << 10));    // 512 KB
    float* psum = (float*)(ws + (2u << 20));                    // 512 KB
    float* xc = (float*)(ws + (2u << 20) + (512u << 10));       // 268.4 MB
    const size_t need_xc =
        (size_t)(2u << 20) + (512u << 10) + (size_t)T_DIM * B_DIM * H_DIM * 4;
    const bool use_xc = (ws_size >= need_xc);

    hipLaunchKernelGGL(k_transpose, dim3(2048), dim3(256), 0, stream,
                       W_hh, W_ih, W_out, whhT, wihT, woutT);
    if (use_xc)
        hipLaunchKernelGGL(k_xc, dim3((T_DIM * B_DIM) / 16), dim3(512), 0, stream,
                           x, wihT, b_ih, b_hh, xc);
    hipLaunchKernelGGL(k_recur, dim3(B_DIM / 4), dim3(256), 0, stream,
                       use_xc ? xc : (const float*)nullptr, x, wihT, b_ih, b_hh,
                       whhT, W_ih, W_halt, b_halt, out, psum);
    hipLaunchKernelGGL(k_y, dim3((T_DIM * B_DIM) / 16), dim3(256), 0, stream,
                       woutT, b_out, psum, out);
}